// Round 16
// baseline (98.403 us; speedup 1.0000x reference)
//
#include <hip/hip_runtime.h>
#include <hip/hip_bf16.h>

typedef unsigned short u16;
typedef __attribute__((ext_vector_type(4))) int   i32x4;
typedef __attribute__((ext_vector_type(4))) float f32x4;

constexpr int N = 8192;
constexpr int D = 1024;
constexpr float INVT = 1.0f / 0.07f;
constexpr int KT = 16;                         // K-tiles (BK=64 i8)
constexpr int NB2 = 128;                       // 8192 / 64 row-blocks
constexpr int NTRI2 = NB2 * (NB2 + 1) / 2;     // 8256 wave-tiles
constexpr int GBLK = NTRI2 / 4;                // 2064 blocks (8 | 2064)
constexpr int PANEL_BYTES = 128 * 1024;        // 128 rows x 1024 i8

// ---- workspace layout (bytes) ----
constexpr size_t OFF_Q8    = 0;                        // 8 MiB tiled q8
constexpr size_t OFF_PSE   = 8388608;                  // 8256*128 f32
constexpr size_t OFF_PPS   = OFF_PSE + 4227072;        // 8256*128 f32
constexpr size_t OFF_SUME  = OFF_PPS + 4227072;        // N f32
constexpr size_t OFF_POSS  = OFF_SUME + 32768;         // N f32
constexpr size_t OFF_TYPE  = OFF_POSS + 32768;         // N i32
constexpr size_t OFF_SCALE = OFF_TYPE + 32768;         // N f32

// one wave per row: normalize, per-row absmax, quantize to i8 into the
// TILED q8 layout (panel p, slot s, row r: byte = p*131072+s*2048+r*16).
__global__ __launch_bounds__(256) void k_norm(
    const float* __restrict__ feat, const long long* __restrict__ et,
    signed char* __restrict__ q8, float* __restrict__ scales,
    int* __restrict__ types) {
  const int t = threadIdx.x;
  const int row = blockIdx.x * 4 + (t >> 6);
  const int l = t & 63;
  const float4* src = (const float4*)(feat + (size_t)row * D);
  float4 v[4];
  float ss = 0.f, ma = 0.f;
  #pragma unroll
  for (int c = 0; c < 4; ++c) {
    v[c] = src[c * 64 + l];
    ss += v[c].x * v[c].x + v[c].y * v[c].y + v[c].z * v[c].z + v[c].w * v[c].w;
    ma = fmaxf(ma, fmaxf(fmaxf(fabsf(v[c].x), fabsf(v[c].y)),
                         fmaxf(fabsf(v[c].z), fabsf(v[c].w))));
  }
  #pragma unroll
  for (int m = 32; m; m >>= 1) {
    ss += __shfl_xor(ss, m);
    ma = fmaxf(ma, __shfl_xor(ma, m));
  }
  const float sc = 1.0f / fmaxf(sqrtf(ss), 1e-12f);
  const float man = ma * sc;
  const float invq = 127.0f / fmaxf(man, 1e-30f);
  const float qf = sc * invq;
  signed char* pb = q8 + (size_t)(row >> 7) * PANEL_BYTES + (row & 127) * 16;
  #pragma unroll
  for (int c = 0; c < 4; ++c) {
    const int b0 = (unsigned char)(signed char)__float2int_rn(v[c].x * qf);
    const int b1 = (unsigned char)(signed char)__float2int_rn(v[c].y * qf);
    const int b2 = (unsigned char)(signed char)__float2int_rn(v[c].z * qf);
    const int b3 = (unsigned char)(signed char)__float2int_rn(v[c].w * qf);
    const int w = c * 64 + l;
    *(int*)(pb + (w >> 2) * 2048 + (w & 3) * 4) =
        b0 | (b1 << 8) | (b2 << 16) | (b3 << 24);
  }
  if (l == 0) {
    scales[row] = man / 127.0f;
    types[row] = (int)et[row];
  }
}

__device__ __forceinline__ void mfma_i8v(i32x4& d, i32x4 a, i32x4 b) {
  asm volatile("v_mfma_i32_16x16x64_i8 %0, %1, %2, %0"
               : "+v"(d) : "v"(a), "v"(b));
}

// 64x64 lower-tri tiles of sim = (q8 . q8^T) * s_i * s_j / T, ONE TILE
// PER WAVE, fully independent (zero barriers, zero LDS/global atomics).
// r14<->r15 showed time tracks resident waves, not per-wave ILP; this
// removes every inter-wave coupling (barriers, shared tables, shared
// slabs, lockstep phases) that could limit residency/packing. Per-wave
// instruction stream = r14's proven 2-deep reg pipeline, identical TA
// traffic and MFMA count. Each wave: stages its own 1KB tables into a
// private LDS slice (same-wave visibility, no sync), K-loop, epilogue,
// one coalesced 256-f32 partial store to partial[w][128].
__global__ __launch_bounds__(256) void k_gemm(
    const signed char* __restrict__ q8, const float* __restrict__ scales,
    const int* __restrict__ types,
    float* __restrict__ pse, float* __restrict__ pps) {
  __shared__ int   rt[4][64], ct[4][64];
  __shared__ float rsl[4][64], csl[4][64];
  __shared__ float s_rse[4][64], s_rps[4][64], s_cse[4][64], s_cps[4][64];

  const int tid = threadIdx.x;
  const int lane = tid & 63;
  const int wid = tid >> 6;

  // XCD swizzle (2064 % 8 == 0) then triangular decode of wave-tile id
  const int pid = blockIdx.x;
  const int swz = (pid & 7) * (GBLK / 8) + (pid >> 3);
  const int w = swz * 4 + wid;                 // 0..8255, canonical tile id
  int rb = (int)((sqrtf(8.0f * (float)w + 1.0f) - 1.0f) * 0.5f);
  while ((rb + 1) * (rb + 2) / 2 <= w) ++rb;
  while (rb * (rb + 1) / 2 > w) --rb;
  const int cb = w - rb * (rb + 1) / 2;
  const int brow = rb * 64, bcol = cb * 64;
  const bool diag = (rb == cb);

  // per-wave tables: written and read by the SAME wave -> no barrier
  rt[wid][lane]  = types[brow + lane];
  rsl[wid][lane] = scales[brow + lane] * INVT;
  ct[wid][lane]  = types[bcol + lane];
  csl[wid][lane] = scales[bcol + lane];

  i32x4 acc[4][4];
  #pragma unroll
  for (int i = 0; i < 4; ++i)
    #pragma unroll
    for (int jj = 0; jj < 4; ++jj) acc[i][jj] = (i32x4){0, 0, 0, 0};

  // fragment base: row (lane&15) of sub-tile, k-slot lane>>4; the 64-row
  // tile lives in half (rb&1) of 128-row panel rb>>1.
  const int slotR = lane >> 4;
  const signed char* pA = q8 + (size_t)(rb >> 1) * PANEL_BYTES +
      (slotR * 128 + (rb & 1) * 64 + (lane & 15)) * 16;
  const signed char* pB = q8 + (size_t)(cb >> 1) * PANEL_BYTES +
      (slotR * 128 + (cb & 1) * 64 + (lane & 15)) * 16;

  i32x4 a0[4], b0[4], a1[4], b1[4];

  #define LOADP(tt, A, B) {                                           \
    const int o = (tt) * 8192;                                        \
    _Pragma("unroll")                                                 \
    for (int q = 0; q < 4; ++q) {                                     \
      A[q] = *(const i32x4*)(pA + o + q * 256);                       \
      B[q] = *(const i32x4*)(pB + o + q * 256);                       \
    } }

  #define MFMAP(A, B) {                                               \
    __builtin_amdgcn_s_setprio(1);                                    \
    _Pragma("unroll")                                                 \
    for (int mi = 0; mi < 4; ++mi)                                    \
      _Pragma("unroll")                                               \
      for (int ni = 0; ni < 4; ++ni) mfma_i8v(acc[mi][ni], A[mi], B[ni]); \
    __builtin_amdgcn_s_setprio(0);                                    \
  }

  LOADP(0, a0, b0)
  LOADP(1, a1, b1)
  for (int t = 0; t < KT; t += 2) {
    MFMAP(a0, b0)
    if (t + 2 < KT) LOADP(t + 2, a0, b0)
    MFMAP(a1, b1)
    if (t + 3 < KT) LOADP(t + 3, a1, b1)
  }

  // MFMA -> VALU read hazard guard
  asm volatile("s_nop 7\n\ts_nop 7\n\ts_nop 7");
  #pragma unroll
  for (int i = 0; i < 4; ++i)
    #pragma unroll
    for (int jj = 0; jj < 4; ++jj) asm volatile("" : "+v"(acc[i][jj]));

  // epilogue: C/D layout col = lane&15, row = (lane>>4)*4 + reg  [m89]
  const int csub = lane & 15;
  const int rsub = (lane >> 4) * 4;
  int gcolv[4], ctv[4];
  float cfv[4];
  #pragma unroll
  for (int ni = 0; ni < 4; ++ni) {
    const int cl = ni * 16 + csub;
    gcolv[ni] = bcol + cl;
    ctv[ni] = ct[wid][cl];
    cfv[ni] = csl[wid][cl];
  }
  float cse[4] = {0.f, 0.f, 0.f, 0.f};
  float cps[4] = {0.f, 0.f, 0.f, 0.f};

  #pragma unroll
  for (int mi = 0; mi < 4; ++mi) {
    #pragma unroll
    for (int r = 0; r < 4; ++r) {
      const int rl = mi * 16 + rsub + r;       // 0..63, unique per (mi,r,grp)
      const int grow = brow + rl;
      const int rty = rt[wid][rl];
      const float rfac = rsl[wid][rl];
      float se = 0.f, ps = 0.f;
      #pragma unroll
      for (int ni = 0; ni < 4; ++ni) {
        const float s = (float)acc[mi][ni][r] * rfac * cfv[ni];
        const float e = __expf(s);
        const bool match = (ctv[ni] == rty);
        if (diag) {
          if (gcolv[ni] != grow) { se += e; if (match) ps += s; }
        } else {
          se += e; if (match) ps += s;
          cse[ni] += e; if (match) cps[ni] += s;
        }
      }
      #pragma unroll
      for (int m = 8; m; m >>= 1) {
        se += __shfl_xor(se, m);
        ps += __shfl_xor(ps, m);
      }
      if (csub == 0) {                         // unique writer per row
        s_rse[wid][rl] = se;
        s_rps[wid][rl] = ps;
      }
    }
  }

  #pragma unroll
  for (int ni = 0; ni < 4; ++ni) {             // col sums (0 for diag)
    float se = cse[ni], ps = cps[ni];
    se += __shfl_xor(se, 16); se += __shfl_xor(se, 32);
    ps += __shfl_xor(ps, 16); ps += __shfl_xor(ps, 32);
    if (lane < 16) {                           // unique writer per col
      s_cse[wid][ni * 16 + lane] = se;
      s_cps[wid][ni * 16 + lane] = ps;
    }
  }

  // coalesced per-wave partial store: [w][0..63]=row-side, [64..127]=col
  const size_t base = (size_t)w * 128;
  pse[base + lane]      = s_rse[wid][lane];
  pse[base + 64 + lane] = s_cse[wid][lane];
  pps[base + lane]      = s_rps[wid][lane];
  pps[base + 64 + lane] = s_cps[wid][lane];
}

// gather partials -> per-row sums (plain stores, no atomics).
// row r: row-side tiles (rb, cb<=rb) at [tc][rr]; col-side tiles
// (i>rb, rb) at [tc][64+rr]. <=255 terms, 2 strided passes per lane.
__global__ __launch_bounds__(256) void k_reduce(
    const float* __restrict__ pse, const float* __restrict__ pps,
    float* __restrict__ sum_exp, float* __restrict__ pos_sum) {
  const int r = blockIdx.x * 4 + (threadIdx.x >> 6);
  const int lane = threadIdx.x & 63;
  const int rb = r >> 6, rr = r & 63;
  float se = 0.f, ps = 0.f;
  for (int cb = lane; cb <= rb; cb += 64) {
    const size_t idx = (size_t)(rb * (rb + 1) / 2 + cb) * 128 + rr;
    se += pse[idx]; ps += pps[idx];
  }
  for (int i = rb + 1 + lane; i < NB2; i += 64) {
    const size_t idx = (size_t)(i * (i + 1) / 2 + rb) * 128 + 64 + rr;
    se += pse[idx]; ps += pps[idx];
  }
  #pragma unroll
  for (int m = 32; m; m >>= 1) {
    se += __shfl_xor(se, m);
    ps += __shfl_xor(ps, m);
  }
  if (lane == 0) { sum_exp[r] = se; pos_sum[r] = ps; }
}

__global__ __launch_bounds__(1024) void k_final(
    const float* __restrict__ sum_exp, const float* __restrict__ pos_sum,
    const int* __restrict__ types, float* __restrict__ out) {
  const int t = threadIdx.x;
  __shared__ int h[32];
  if (t < 32) h[t] = 0;
  __syncthreads();
  int ty[8];
  #pragma unroll
  for (int i = 0; i < 8; ++i) {
    ty[i] = types[t + i * 1024];
    atomicAdd(&h[ty[i]], 1);
  }
  __syncthreads();
  float ls = 0.f, cnt = 0.f;
  #pragma unroll
  for (int i = 0; i < 8; ++i) {
    const int r = t + i * 1024;
    const int pc = h[ty[i]] - 1;
    if (pc > 0) {
      const float pm = pos_sum[r] / (float)pc;
      ls += -logf(__expf(pm) / sum_exp[r] + 1e-10f);
      cnt += 1.f;
    }
  }
  #pragma unroll
  for (int m = 32; m; m >>= 1) {
    ls += __shfl_xor(ls, m);
    cnt += __shfl_xor(cnt, m);
  }
  __shared__ float s1[16], s2[16];
  if ((t & 63) == 0) { s1[t >> 6] = ls; s2[t >> 6] = cnt; }
  __syncthreads();
  if (t == 0) {
    float T = 0.f, C = 0.f;
    for (int i = 0; i < 16; ++i) { T += s1[i]; C += s2[i]; }
    out[0] = (C > 0.f) ? T / C : 0.f;
  }
}

extern "C" void kernel_launch(void* const* d_in, const int* in_sizes, int n_in,
                              void* d_out, int out_size, void* d_ws, size_t ws_size,
                              hipStream_t stream) {
  const float* feat = (const float*)d_in[0];
  const long long* et = (const long long*)d_in[1];
  char* ws = (char*)d_ws;
  signed char* q8 = (signed char*)(ws + OFF_Q8);
  float* pse    = (float*)(ws + OFF_PSE);
  float* pps    = (float*)(ws + OFF_PPS);
  float* sum_e  = (float*)(ws + OFF_SUME);
  float* pos_s  = (float*)(ws + OFF_POSS);
  int* types    = (int*)(ws + OFF_TYPE);
  float* scale  = (float*)(ws + OFF_SCALE);
  float* out    = (float*)d_out;

  k_norm<<<N / 4, 256, 0, stream>>>(feat, et, q8, scale, types);
  k_gemm<<<GBLK, 256, 0, stream>>>(q8, scale, types, pse, pps);
  k_reduce<<<N / 4, 256, 0, stream>>>(pse, pps, sum_e, pos_s);
  k_final<<<1, 1024, 0, stream>>>(sum_e, pos_s, types, out);
}